// Round 1
// baseline (664.316 us; speedup 1.0000x reference)
//
#include <hip/hip_runtime.h>
#include <cmath>

#define N_NODES 100000
#define N_EDGES 1600000
#define F_IN 512
#define F_HID 128
#define F_OUT 64

#define SCAN_NB ((N_NODES + 255) / 256)   // 391 blocks

// ---- bucketed CSR-build params ----
#define BK_SHIFT 10                        // 1024 nodes per bucket
#define NBUK ((N_NODES + 1023) >> 10)      // 98 buckets
#define SCAP 24576                         // staging capacity/bucket (mean 16327, +65 sigma)
#define LSLOT 64                           // LDS slots per bucket
#define NBLK_A 128                         // partition blocks
#define OV_CAP 4096                        // global overflow records

typedef __attribute__((ext_vector_type(8))) short short8;
typedef __attribute__((ext_vector_type(4))) float float4v;

__device__ __forceinline__ unsigned short f2bf(float f) {
    unsigned u = __builtin_bit_cast(unsigned, f);
    u += 0x7FFFu + ((u >> 16) & 1u);   // RNE
    return (unsigned short)(u >> 16);
}
__device__ __forceinline__ float bf2f(unsigned short s) {
    unsigned u = ((unsigned)s) << 16;
    return __builtin_bit_cast(float, u);
}
__device__ __forceinline__ float lo_bf(unsigned u) {
    return __builtin_bit_cast(float, u << 16);
}
__device__ __forceinline__ float hi_bf(unsigned u) {
    return __builtin_bit_cast(float, u & 0xFFFF0000u);
}
__device__ __forceinline__ short8 cvt8(float4 lo, float4 hi) {
    return short8{(short)f2bf(lo.x), (short)f2bf(lo.y), (short)f2bf(lo.z), (short)f2bf(lo.w),
                  (short)f2bf(hi.x), (short)f2bf(hi.y), (short)f2bf(hi.z), (short)f2bf(hi.w)};
}

// ---------------- partition: edges -> per-bucket staging (+deg count fused) ----------------
// LDS multisplit: drain only full 16-rec (64B) groups so staging writes are
// dense full lines appended by per-bucket global cursors. One CSR line is
// later written by exactly one block (one XCD L2) -> no write amplification.
__global__ __launch_bounds__(256) void partition_kernel(
    const int* __restrict__ src, const int* __restrict__ dst,
    int* __restrict__ deg, unsigned* __restrict__ staging, int* __restrict__ gcur,
    unsigned long long* __restrict__ ovbuf, int* __restrict__ ovcnt) {
    __shared__ unsigned buf[NBUK][LSLOT];
    __shared__ int cnt[NBUK];
    int tid = threadIdx.x;
    for (int b = tid; b < NBUK; b += 256) cnt[b] = 0;
    __syncthreads();
    const int PER = (N_EDGES + NBLK_A - 1) / NBLK_A;   // 12500
    int e0 = blockIdx.x * PER;
    int e1 = min(e0 + PER, N_EDGES);
    for (int base = e0; base < e1; base += 1024) {
#pragma unroll
        for (int t = 0; t < 4; ++t) {
            int e = base + t * 256 + tid;
            if (e < e1) {
                int d = dst[e];
                int s = src[e];
                atomicAdd(&deg[d], 1);
                int b = d >> BK_SHIFT;
                unsigned rec = (unsigned)s | ((unsigned)(d & 1023) << 17);
                int slot = atomicAdd(&cnt[b], 1);
                if (slot < LSLOT) {
                    buf[b][slot] = rec;
                } else {  // rare LDS overflow: spill (src,dst) to global list
                    int op = atomicAdd(ovcnt, 1);
                    if (op < OV_CAP)
                        ovbuf[op] = ((unsigned long long)(unsigned)d << 32) | (unsigned)s;
                }
            }
        }
        __syncthreads();
        // drain full 16-record groups, carry remainder (<16)
        for (int b = tid; b < NBUK; b += 256) {
            int c = min(cnt[b], LSLOT);
            int full = c & ~15;
            if (full > 0) {
                int pos = atomicAdd(&gcur[b], full);
                if (pos + full <= SCAP) {
                    unsigned* dp = &staging[(size_t)b * SCAP + pos];
                    for (int i = 0; i < full; ++i) dp[i] = buf[b][i];
                }
                for (int i = 0; i < c - full; ++i) buf[b][i] = buf[b][full + i];
            }
            cnt[b] = c - full;
        }
        __syncthreads();
    }
    // final flush of remainders
    for (int b = tid; b < NBUK; b += 256) {
        int c = cnt[b];
        if (c > 0) {
            int pos = atomicAdd(&gcur[b], c);
            if (pos + c <= SCAP)
                for (int i = 0; i < c; ++i) staging[(size_t)b * SCAP + pos + i] = buf[b][i];
        }
    }
}

// ---------------- fill: one block per bucket -> single-XCD-local CSR scatter ----------------
__global__ __launch_bounds__(256) void fill_kernel(
    const unsigned* __restrict__ staging, const int* __restrict__ gcur,
    int* __restrict__ cursor, int* __restrict__ csr_src,
    const unsigned long long* __restrict__ ovbuf, const int* __restrict__ ovcnt) {
    int b = blockIdx.x;
    int node0 = b << BK_SHIFT;
    int n = gcur[b];
    if (n > SCAP) n = SCAP;
    const unsigned* sp = &staging[(size_t)b * SCAP];
    for (int i = threadIdx.x; i < n; i += 256) {
        unsigned rec = sp[i];
        int s = (int)(rec & 0x1FFFFu);
        int d = node0 + (int)(rec >> 17);
        int pos = atomicAdd(&cursor[d], 1);
        csr_src[pos] = s;
    }
    int oc = *ovcnt;
    if (oc > OV_CAP) oc = OV_CAP;
    for (int i = threadIdx.x; i < oc; i += 256) {
        unsigned long long r = ovbuf[i];
        int d = (int)(r >> 32);
        if ((d >> BK_SHIFT) == b) {
            int pos = atomicAdd(&cursor[d], 1);
            csr_src[pos] = (int)(r & 0xffffffffu);
        }
    }
}

// ---------------- scans ----------------

__global__ __launch_bounds__(256) void block_sum_kernel(const int* __restrict__ deg,
                                                        int* __restrict__ bsum, int n) {
    int g = blockIdx.x * 256 + threadIdx.x;
    int v = (g < n) ? deg[g] : 0;
    __shared__ int ws[4];
    int lane = threadIdx.x & 63;
    int w = threadIdx.x >> 6;
#pragma unroll
    for (int o = 32; o > 0; o >>= 1) v += __shfl_down(v, o, 64);
    if (lane == 0) ws[w] = v;
    __syncthreads();
    if (threadIdx.x == 0) bsum[blockIdx.x] = ws[0] + ws[1] + ws[2] + ws[3];
}

__global__ __launch_bounds__(512) void scan_partials_kernel(int* __restrict__ bsum, int nb) {
    __shared__ int t[512];
    int tid = threadIdx.x;
    int v = (tid < nb) ? bsum[tid] : 0;
    t[tid] = v;
    __syncthreads();
    for (int d = 1; d < 512; d <<= 1) {
        int u = (tid >= d) ? t[tid - d] : 0;
        __syncthreads();
        t[tid] += u;
        __syncthreads();
    }
    if (tid < nb) bsum[tid] = t[tid] - v;  // exclusive
}

__global__ __launch_bounds__(256) void scan_final_kernel(const int* __restrict__ deg,
                                                         const int* __restrict__ bsum,
                                                         int* __restrict__ row_ptr,
                                                         int* __restrict__ cursor,
                                                         float* __restrict__ dinv, int n) {
    __shared__ int t[256];
    int g = blockIdx.x * 256 + threadIdx.x;
    int tid = threadIdx.x;
    int v = (g < n) ? deg[g] : 0;
    t[tid] = v;
    __syncthreads();
    for (int d = 1; d < 256; d <<= 1) {
        int u = (tid >= d) ? t[tid - d] : 0;
        __syncthreads();
        t[tid] += u;
        __syncthreads();
    }
    int off = bsum[blockIdx.x] + t[tid] - v;
    if (g < n) {
        row_ptr[g] = off;
        cursor[g] = off;
        dinv[g] = rsqrtf((float)(v + 1));
    }
    if (g == n - 1) row_ptr[n] = off + v;
}

// ---------------- W transpose+convert: Wt[n][k] bf16 ----------------

__global__ void transpose_w_kernel(const float* __restrict__ W1, const float* __restrict__ W2,
                                   unsigned short* __restrict__ Wt1,
                                   unsigned short* __restrict__ Wt2) {
    int g = blockIdx.x * 256 + threadIdx.x;
    if (g < F_HID * F_IN) {               // Wt1: [128][512]
        int n = g >> 9, k = g & 511;
        Wt1[g] = f2bf(W1[k * F_HID + n]);
    } else {
        int h = g - F_HID * F_IN;         // Wt2: [64][128]
        if (h < F_OUT * F_HID) {
            int n = h >> 7, k = h & 127;
            Wt2[h] = f2bf(W2[k * F_OUT + n]);
        }
    }
}

// ---------------- barrier-free direct-load MFMA GEMM, register double-buffered ----------------
// R5: explicit two-deep register pipeline. Named cur/next operand regs (all
// compile-time indices), loads for step k+1 issued a full MFMA cluster before
// use -> 12 loads (12KB) stay in flight per wave across each MFMA step.
// __launch_bounds__(256,2) lifts the 92-VGPR occupancy-heuristic cap that was
// serializing the loads (R4 counters: MfmaUtil 4%, HBM 13%, 18.5k cyc/k-step).

template <int BN, int K, bool A_BF16>
__global__ __launch_bounds__(256, 2) void gemm_direct_kernel(
    const void* __restrict__ Araw, const unsigned short* __restrict__ Wt,
    const float* __restrict__ dinv, unsigned short* __restrict__ out, int N) {
    constexpr int NCT = BN / 16;
    int lane = threadIdx.x & 63;
    int wv = threadIdx.x >> 6;
    int row0 = blockIdx.x * 128 + wv * 32;
    if (row0 >= N) return;                 // no barriers in kernel: safe
    int l15 = lane & 15;
    int q = lane >> 4;
    int q8 = q * 8;
    int r0 = row0 + l15;
    int r1 = r0 + 16;
    size_t r0c = (size_t)(r0 < N ? r0 : N - 1);
    size_t r1c = (size_t)(r1 < N ? r1 : N - 1);

    const unsigned short* Ab = (const unsigned short*)Araw;
    const float* Af = (const float*)Araw;

    float4v acc[2][NCT] = {};

    // double-buffered raw operand registers (names, not runtime-indexed arrays)
    short8 a0_0, a1_0, a0_1, a1_1;                 // bf16-path raw A
    float4 x0_0, x1_0, y0_0, y1_0;                 // fp32-path raw A, buf 0
    float4 x0_1, x1_1, y0_1, y1_1;                 // fp32-path raw A, buf 1
    short8 b_0[NCT], b_1[NCT];

#define LOADA(B_, K0)                                                          \
    do {                                                                       \
        if constexpr (A_BF16) {                                                \
            a0_##B_ = *(const short8*)&Ab[r0c * K + (K0) + q8];                \
            a1_##B_ = *(const short8*)&Ab[r1c * K + (K0) + q8];                \
        } else {                                                               \
            x0_##B_ = *(const float4*)&Af[r0c * K + (K0) + q8];                \
            x1_##B_ = *(const float4*)&Af[r0c * K + (K0) + q8 + 4];            \
            y0_##B_ = *(const float4*)&Af[r1c * K + (K0) + q8];                \
            y1_##B_ = *(const float4*)&Af[r1c * K + (K0) + q8 + 4];            \
        }                                                                      \
    } while (0)

#define LOADB(B_, K0)                                                          \
    do {                                                                       \
        _Pragma("unroll")                                                      \
        for (int ct = 0; ct < NCT; ++ct)                                       \
            b_##B_[ct] = *(const short8*)&Wt[(size_t)(ct * 16 + l15) * K + (K0) + q8]; \
    } while (0)

#define STEP(B_)                                                               \
    do {                                                                       \
        short8 A0, A1;                                                         \
        if constexpr (A_BF16) {                                                \
            A0 = a0_##B_;                                                      \
            A1 = a1_##B_;                                                      \
        } else {                                                               \
            A0 = cvt8(x0_##B_, x1_##B_);                                       \
            A1 = cvt8(y0_##B_, y1_##B_);                                       \
        }                                                                      \
        _Pragma("unroll")                                                      \
        for (int ct = 0; ct < NCT; ++ct) {                                     \
            acc[0][ct] = __builtin_amdgcn_mfma_f32_16x16x32_bf16(A0, b_##B_[ct], acc[0][ct], 0, 0, 0); \
            acc[1][ct] = __builtin_amdgcn_mfma_f32_16x16x32_bf16(A1, b_##B_[ct], acc[1][ct], 0, 0, 0); \
        }                                                                      \
    } while (0)

    // prologue: fill both buffers (k=0, k=32)
    LOADA(0, 0);
    LOADB(0, 0);
    LOADA(1, 32);
    LOADB(1, 32);
    // steady state: consume buf, immediately refill it for k0(+32); the refill
    // has a full MFMA step of slack before its own consumption.
#pragma unroll 1
    for (int k0 = 64; k0 < K; k0 += 64) {
        STEP(0);
        LOADA(0, k0);
        LOADB(0, k0);
        STEP(1);
        LOADA(1, k0 + 32);
        LOADB(1, k0 + 32);
    }
    STEP(0);
    STEP(1);

#undef LOADA
#undef LOADB
#undef STEP

#pragma unroll
    for (int rt = 0; rt < 2; ++rt) {
#pragma unroll
        for (int reg = 0; reg < 4; ++reg) {
            int row = row0 + rt * 16 + q * 4 + reg;
            if (row < N) {
                float sc = dinv[row];
#pragma unroll
                for (int ct = 0; ct < NCT; ++ct) {
                    out[(size_t)row * BN + ct * 16 + l15] = f2bf(acc[rt][ct][reg] * sc);
                }
            }
        }
    }
}

// ---------------- aggregation (bf16 in, fp32 accumulate) ----------------
__global__ __launch_bounds__(256) void agg1_kernel(
    const unsigned int* __restrict__ g1, const int* __restrict__ row_ptr,
    const int* __restrict__ csr_src, const float* __restrict__ dinv,
    const float* __restrict__ b1, unsigned int* __restrict__ h1) {
    int node = blockIdx.x * 4 + (threadIdx.x >> 6);
    int lane = threadIdx.x & 63;
    if (node >= N_NODES) return;
    unsigned u = g1[(size_t)node * 64 + lane];
    float a0 = lo_bf(u), a1 = hi_bf(u);
    int e = row_ptr[node], end = row_ptr[node + 1];
    for (; e + 4 <= end; e += 4) {
        int j0 = csr_src[e], j1 = csr_src[e + 1], j2 = csr_src[e + 2], j3 = csr_src[e + 3];
        unsigned u0 = g1[(size_t)j0 * 64 + lane];
        unsigned u1 = g1[(size_t)j1 * 64 + lane];
        unsigned u2 = g1[(size_t)j2 * 64 + lane];
        unsigned u3 = g1[(size_t)j3 * 64 + lane];
        a0 += lo_bf(u0) + lo_bf(u1) + lo_bf(u2) + lo_bf(u3);
        a1 += hi_bf(u0) + hi_bf(u1) + hi_bf(u2) + hi_bf(u3);
    }
    for (; e < end; ++e) {
        unsigned u0 = g1[(size_t)csr_src[e] * 64 + lane];
        a0 += lo_bf(u0);
        a1 += hi_bf(u0);
    }
    float d = dinv[node];
    float v0 = fmaxf(d * a0 + b1[2 * lane], 0.0f);
    float v1 = fmaxf(d * a1 + b1[2 * lane + 1], 0.0f);
    h1[(size_t)node * 64 + lane] = (unsigned)f2bf(v0) | ((unsigned)f2bf(v1) << 16);
}

__global__ __launch_bounds__(256) void agg2_lsm_kernel(
    const unsigned short* __restrict__ g2, const int* __restrict__ row_ptr,
    const int* __restrict__ csr_src, const float* __restrict__ dinv,
    const float* __restrict__ b2, float* __restrict__ out) {
    int node = blockIdx.x * 4 + (threadIdx.x >> 6);
    int lane = threadIdx.x & 63;
    if (node >= N_NODES) return;
    float a = bf2f(g2[(size_t)node * 64 + lane]);
    int e = row_ptr[node], end = row_ptr[node + 1];
    for (; e + 4 <= end; e += 4) {
        int j0 = csr_src[e], j1 = csr_src[e + 1], j2 = csr_src[e + 2], j3 = csr_src[e + 3];
        a += bf2f(g2[(size_t)j0 * 64 + lane]) + bf2f(g2[(size_t)j1 * 64 + lane]) +
             bf2f(g2[(size_t)j2 * 64 + lane]) + bf2f(g2[(size_t)j3 * 64 + lane]);
    }
    for (; e < end; ++e) a += bf2f(g2[(size_t)csr_src[e] * 64 + lane]);
    float v = dinv[node] * a + b2[lane];
    float m = v;
#pragma unroll
    for (int o = 32; o > 0; o >>= 1) m = fmaxf(m, __shfl_xor(m, o, 64));
    float ex = __expf(v - m);
    float s = ex;
#pragma unroll
    for (int o = 32; o > 0; o >>= 1) s += __shfl_xor(s, o, 64);
    out[(size_t)node * 64 + lane] = v - m - __logf(s);
}

// ---------------- launch ----------------

extern "C" void kernel_launch(void* const* d_in, const int* in_sizes, int n_in,
                              void* d_out, int out_size, void* d_ws, size_t ws_size,
                              hipStream_t stream) {
    const float* x  = (const float*)d_in[0];
    const int* eidx = (const int*)d_in[1];
    const float* W1 = (const float*)d_in[2];
    const float* b1 = (const float*)d_in[3];
    const float* W2 = (const float*)d_in[4];
    const float* b2 = (const float*)d_in[5];
    float* out = (float*)d_out;
    const int* src = eidx;
    const int* dst = eidx + N_EDGES;

    char* base = (char*)d_ws;
    size_t off = 0;
    auto alloc = [&](size_t bytes) -> void* {
        void* p = base + off;
        off += (bytes + 255) & ~(size_t)255;
        return p;
    };
    // zero-init region: [deg | gcur | ovcnt] — one memset
    int* zbase    = (int*)alloc((size_t)(N_NODES + NBUK + 64) * 4);
    int* deg      = zbase;
    int* gcur     = zbase + N_NODES;
    int* ovcnt    = zbase + N_NODES + NBUK;
    int* row_ptr  = (int*)alloc((size_t)(N_NODES + 1) * 4);
    int* cursor   = (int*)alloc((size_t)N_NODES * 4);
    float* dinv   = (float*)alloc((size_t)N_NODES * 4);
    int* bsum     = (int*)alloc((size_t)SCAN_NB * 4);
    unsigned* staging = (unsigned*)alloc((size_t)NBUK * SCAP * 4);   // 9.6 MB
    unsigned long long* ovbuf = (unsigned long long*)alloc((size_t)OV_CAP * 8);
    int* csr_src  = (int*)alloc((size_t)N_EDGES * 4);
    unsigned short* Wt1 = (unsigned short*)alloc((size_t)F_HID * F_IN * 2);
    unsigned short* Wt2 = (unsigned short*)alloc((size_t)F_OUT * F_HID * 2);
    unsigned short* g1  = (unsigned short*)alloc((size_t)N_NODES * F_HID * 2);
    unsigned short* h1  = (unsigned short*)alloc((size_t)N_NODES * F_HID * 2);
    unsigned short* g2  = g1;  // g1 dead after agg1

    hipMemsetAsync(zbase, 0, (size_t)(N_NODES + NBUK + 64) * 4, stream);
    partition_kernel<<<NBLK_A, 256, 0, stream>>>(src, dst, deg, staging, gcur, ovbuf, ovcnt);
    block_sum_kernel<<<SCAN_NB, 256, 0, stream>>>(deg, bsum, N_NODES);
    scan_partials_kernel<<<1, 512, 0, stream>>>(bsum, SCAN_NB);
    scan_final_kernel<<<SCAN_NB, 256, 0, stream>>>(deg, bsum, row_ptr, cursor, dinv, N_NODES);
    fill_kernel<<<NBUK, 256, 0, stream>>>(staging, gcur, cursor, csr_src, ovbuf, ovcnt);
    transpose_w_kernel<<<(F_HID * F_IN + F_OUT * F_HID + 255) / 256, 256, 0, stream>>>(
        W1, W2, Wt1, Wt2);

    int gblocks = (N_NODES + 127) / 128;  // 782
    gemm_direct_kernel<F_HID, F_IN, false><<<gblocks, 256, 0, stream>>>(
        (const void*)x, Wt1, dinv, g1, N_NODES);
    agg1_kernel<<<(N_NODES + 3) / 4, 256, 0, stream>>>(
        (const unsigned int*)g1, row_ptr, csr_src, dinv, b1, (unsigned int*)h1);

    gemm_direct_kernel<F_OUT, F_HID, true><<<gblocks, 256, 0, stream>>>(
        (const void*)h1, Wt2, dinv, g2, N_NODES);
    agg2_lsm_kernel<<<(N_NODES + 3) / 4, 256, 0, stream>>>(
        g2, row_ptr, csr_src, dinv, b2, out);
}

// Round 2
// 636.801 us; speedup vs baseline: 1.0432x; 1.0432x over previous
//
#include <hip/hip_runtime.h>
#include <cmath>

#define N_NODES 100000
#define N_EDGES 1600000
#define F_IN 512
#define F_HID 128
#define F_OUT 64

#define SCAN_NB ((N_NODES + 255) / 256)   // 391 blocks

// ---- bucketed CSR-build params ----
#define BK_SHIFT 10                        // 1024 nodes per bucket
#define NBUK ((N_NODES + 1023) >> 10)      // 98 buckets
#define SCAP 24576                         // staging capacity/bucket (mean 16327, +65 sigma)
#define LSLOT 64                           // LDS slots per bucket
#define NBLK_A 128                         // partition blocks
#define OV_CAP 4096                        // global overflow records

typedef __attribute__((ext_vector_type(8))) short short8;
typedef __attribute__((ext_vector_type(4))) float float4v;

// async global->LDS, 16B per lane; LDS dest is wave-uniform base + lane*16
#define GLOAD_LDS16(g, l)                                                      \
    __builtin_amdgcn_global_load_lds(                                          \
        (const __attribute__((address_space(1))) void*)(g),                    \
        (__attribute__((address_space(3))) void*)(l), 16, 0, 0)

__device__ __forceinline__ unsigned short f2bf(float f) {
    unsigned u = __builtin_bit_cast(unsigned, f);
    u += 0x7FFFu + ((u >> 16) & 1u);   // RNE
    return (unsigned short)(u >> 16);
}
__device__ __forceinline__ float bf2f(unsigned short s) {
    unsigned u = ((unsigned)s) << 16;
    return __builtin_bit_cast(float, u);
}
__device__ __forceinline__ float lo_bf(unsigned u) {
    return __builtin_bit_cast(float, u << 16);
}
__device__ __forceinline__ float hi_bf(unsigned u) {
    return __builtin_bit_cast(float, u & 0xFFFF0000u);
}
__device__ __forceinline__ short8 cvt8(float4 lo, float4 hi) {
    return short8{(short)f2bf(lo.x), (short)f2bf(lo.y), (short)f2bf(lo.z), (short)f2bf(lo.w),
                  (short)f2bf(hi.x), (short)f2bf(hi.y), (short)f2bf(hi.z), (short)f2bf(hi.w)};
}

// ---------------- partition: edges -> per-bucket staging (+deg count fused) ----------------
__global__ __launch_bounds__(256) void partition_kernel(
    const int* __restrict__ src, const int* __restrict__ dst,
    int* __restrict__ deg, unsigned* __restrict__ staging, int* __restrict__ gcur,
    unsigned long long* __restrict__ ovbuf, int* __restrict__ ovcnt) {
    __shared__ unsigned buf[NBUK][LSLOT];
    __shared__ int cnt[NBUK];
    int tid = threadIdx.x;
    for (int b = tid; b < NBUK; b += 256) cnt[b] = 0;
    __syncthreads();
    const int PER = (N_EDGES + NBLK_A - 1) / NBLK_A;   // 12500
    int e0 = blockIdx.x * PER;
    int e1 = min(e0 + PER, N_EDGES);
    for (int base = e0; base < e1; base += 1024) {
#pragma unroll
        for (int t = 0; t < 4; ++t) {
            int e = base + t * 256 + tid;
            if (e < e1) {
                int d = dst[e];
                int s = src[e];
                atomicAdd(&deg[d], 1);
                int b = d >> BK_SHIFT;
                unsigned rec = (unsigned)s | ((unsigned)(d & 1023) << 17);
                int slot = atomicAdd(&cnt[b], 1);
                if (slot < LSLOT) {
                    buf[b][slot] = rec;
                } else {  // rare LDS overflow: spill (src,dst) to global list
                    int op = atomicAdd(ovcnt, 1);
                    if (op < OV_CAP)
                        ovbuf[op] = ((unsigned long long)(unsigned)d << 32) | (unsigned)s;
                }
            }
        }
        __syncthreads();
        // drain full 16-record groups, carry remainder (<16)
        for (int b = tid; b < NBUK; b += 256) {
            int c = min(cnt[b], LSLOT);
            int full = c & ~15;
            if (full > 0) {
                int pos = atomicAdd(&gcur[b], full);
                if (pos + full <= SCAP) {
                    unsigned* dp = &staging[(size_t)b * SCAP + pos];
                    for (int i = 0; i < full; ++i) dp[i] = buf[b][i];
                }
                for (int i = 0; i < c - full; ++i) buf[b][i] = buf[b][full + i];
            }
            cnt[b] = c - full;
        }
        __syncthreads();
    }
    // final flush of remainders
    for (int b = tid; b < NBUK; b += 256) {
        int c = cnt[b];
        if (c > 0) {
            int pos = atomicAdd(&gcur[b], c);
            if (pos + c <= SCAP)
                for (int i = 0; i < c; ++i) staging[(size_t)b * SCAP + pos + i] = buf[b][i];
        }
    }
}

// ---------------- fill: one block per bucket -> single-XCD-local CSR scatter ----------------
__global__ __launch_bounds__(256) void fill_kernel(
    const unsigned* __restrict__ staging, const int* __restrict__ gcur,
    int* __restrict__ cursor, int* __restrict__ csr_src,
    const unsigned long long* __restrict__ ovbuf, const int* __restrict__ ovcnt) {
    int b = blockIdx.x;
    int node0 = b << BK_SHIFT;
    int n = gcur[b];
    if (n > SCAP) n = SCAP;
    const unsigned* sp = &staging[(size_t)b * SCAP];
    for (int i = threadIdx.x; i < n; i += 256) {
        unsigned rec = sp[i];
        int s = (int)(rec & 0x1FFFFu);
        int d = node0 + (int)(rec >> 17);
        int pos = atomicAdd(&cursor[d], 1);
        csr_src[pos] = s;
    }
    int oc = *ovcnt;
    if (oc > OV_CAP) oc = OV_CAP;
    for (int i = threadIdx.x; i < oc; i += 256) {
        unsigned long long r = ovbuf[i];
        int d = (int)(r >> 32);
        if ((d >> BK_SHIFT) == b) {
            int pos = atomicAdd(&cursor[d], 1);
            csr_src[pos] = (int)(r & 0xffffffffu);
        }
    }
}

// ---------------- scans ----------------

__global__ __launch_bounds__(256) void block_sum_kernel(const int* __restrict__ deg,
                                                        int* __restrict__ bsum, int n) {
    int g = blockIdx.x * 256 + threadIdx.x;
    int v = (g < n) ? deg[g] : 0;
    __shared__ int ws[4];
    int lane = threadIdx.x & 63;
    int w = threadIdx.x >> 6;
#pragma unroll
    for (int o = 32; o > 0; o >>= 1) v += __shfl_down(v, o, 64);
    if (lane == 0) ws[w] = v;
    __syncthreads();
    if (threadIdx.x == 0) bsum[blockIdx.x] = ws[0] + ws[1] + ws[2] + ws[3];
}

__global__ __launch_bounds__(512) void scan_partials_kernel(int* __restrict__ bsum, int nb) {
    __shared__ int t[512];
    int tid = threadIdx.x;
    int v = (tid < nb) ? bsum[tid] : 0;
    t[tid] = v;
    __syncthreads();
    for (int d = 1; d < 512; d <<= 1) {
        int u = (tid >= d) ? t[tid - d] : 0;
        __syncthreads();
        t[tid] += u;
        __syncthreads();
    }
    if (tid < nb) bsum[tid] = t[tid] - v;  // exclusive
}

__global__ __launch_bounds__(256) void scan_final_kernel(const int* __restrict__ deg,
                                                         const int* __restrict__ bsum,
                                                         int* __restrict__ row_ptr,
                                                         int* __restrict__ cursor,
                                                         float* __restrict__ dinv, int n) {
    __shared__ int t[256];
    int g = blockIdx.x * 256 + threadIdx.x;
    int tid = threadIdx.x;
    int v = (g < n) ? deg[g] : 0;
    t[tid] = v;
    __syncthreads();
    for (int d = 1; d < 256; d <<= 1) {
        int u = (tid >= d) ? t[tid - d] : 0;
        __syncthreads();
        t[tid] += u;
        __syncthreads();
    }
    int off = bsum[blockIdx.x] + t[tid] - v;
    if (g < n) {
        row_ptr[g] = off;
        cursor[g] = off;
        dinv[g] = rsqrtf((float)(v + 1));
    }
    if (g == n - 1) row_ptr[n] = off + v;
}

// ---------------- W transpose+convert: Wt[n][k] bf16 ----------------

__global__ void transpose_w_kernel(const float* __restrict__ W1, const float* __restrict__ W2,
                                   unsigned short* __restrict__ Wt1,
                                   unsigned short* __restrict__ Wt2) {
    int g = blockIdx.x * 256 + threadIdx.x;
    if (g < F_HID * F_IN) {               // Wt1: [128][512]
        int n = g >> 9, k = g & 511;
        Wt1[g] = f2bf(W1[k * F_HID + n]);
    } else {
        int h = g - F_HID * F_IN;         // Wt2: [64][128]
        if (h < F_OUT * F_HID) {
            int n = h >> 7, k = h & 127;
            Wt2[h] = f2bf(W2[k * F_OUT + n]);
        }
    }
}

// ---------------- m97-style LDS-staged MFMA GEMM ----------------
// R6: R5's register double-buffer could cover only ~80 cyc of ~900-cyc load
// latency (16 MFMA/step) -> loads stayed serialized (MfmaUtil 4%, HBM 13%).
// Fix: async global_load_lds staging into double-buffered LDS, one barrier
// per 32-k step. 48KB LDS -> 3 blocks/CU; phase-offset blocks cover each
// other's vmcnt-drain stall and keep ~40-70KB/CU of HBM loads in flight
// (Little's law needs ~15KB/CU for 6.3 TB/s).
// Bank-conflict fix (both-sides-or-neither, rule #21): LDS dest stays linear,
// the 16B source slot is XOR-swizzled (g = s ^ (row&MASK)), and ds_read
// applies the same XOR -> verified uniform 8 lanes per 16B bank-group.

template <int BN, int K, bool A_BF16>
__global__ __launch_bounds__(256, 3) void gemm_lds_kernel(
    const void* __restrict__ Araw, const unsigned short* __restrict__ Wt,
    const float* __restrict__ dinv, unsigned short* __restrict__ out, int N) {
    constexpr int NCT = BN / 16;
    constexpr int AE = A_BF16 ? 2 : 4;         // A element bytes
    constexpr int SLOTS_A = (32 * AE) / 16;    // 16B slots per row per 32-k chunk (4 or 8)
    constexpr int MA = SLOTS_A - 1;
    constexpr int ABYTES = 128 * 32 * AE;      // per A buffer (8K or 16K)
    constexpr int BBYTES = BN * 32 * 2;        // per B buffer (4K or 8K)
    constexpr int NT = K / 32;

    __shared__ __align__(128) char Abuf[2][ABYTES];
    __shared__ __align__(128) char Bbuf[2][BBYTES];

    const char* Ab = (const char*)Araw;
    const char* Bb = (const char*)Wt;
    int tid = threadIdx.x;
    int lane = tid & 63;
    int wv = tid >> 6;
    int row0 = blockIdx.x * 128;
    int l15 = lane & 15;
    int q = lane >> 4;

    float4v acc[2][NCT] = {};

    auto stage = [&](int buf, int k0) {
        // A: 128 rows x 32 elems, 16B chunks; chunk c -> row c/SLOTS_A, slot c%SLOTS_A
        constexpr int CA = 128 * SLOTS_A;
#pragma unroll
        for (int i = 0; i < CA / 256; ++i) {
            int c = i * 256 + tid;
            int cw = i * 256 + (tid & ~63);      // wave-uniform chunk base
            int row = c / SLOTS_A;
            int s = c & MA;
            int g = s ^ (row & MA);              // inverse swizzle on SOURCE
            int rg = row0 + row;
            if (rg >= N) rg = N - 1;             // clamp (last block tail)
            GLOAD_LDS16(Ab + ((size_t)rg * K + k0) * AE + g * 16,
                        &Abuf[buf][cw * 16]);
        }
        // B: BN cols x 32 k bf16 (64B per col = 4 slots)
        constexpr int CB = BN * 4;
#pragma unroll
        for (int i = 0; i < CB / 256; ++i) {
            int c = i * 256 + tid;
            int cw = i * 256 + (tid & ~63);
            int col = c >> 2;
            int s = c & 3;
            int g = s ^ (col & 3);
            GLOAD_LDS16(Bb + ((size_t)col * K + k0) * 2 + g * 16,
                        &Bbuf[buf][cw * 16]);
        }
    };

    auto compute = [&](int buf) {
        const char* Ac = Abuf[buf];
        const char* Bc = Bbuf[buf];
        int lr0 = wv * 32 + l15;
        int lr1 = lr0 + 16;
        short8 a0, a1;
        if constexpr (A_BF16) {
            int s0 = q ^ (lr0 & 3);
            int s1 = q ^ (lr1 & 3);
            a0 = *(const short8*)(Ac + lr0 * 64 + s0 * 16);
            a1 = *(const short8*)(Ac + lr1 * 64 + s1 * 16);
        } else {
            int r7a = lr0 & 7, r7b = lr1 & 7;
            float4 f0 = *(const float4*)(Ac + lr0 * 128 + ((2 * q) ^ r7a) * 16);
            float4 f1 = *(const float4*)(Ac + lr0 * 128 + ((2 * q + 1) ^ r7a) * 16);
            float4 f2 = *(const float4*)(Ac + lr1 * 128 + ((2 * q) ^ r7b) * 16);
            float4 f3 = *(const float4*)(Ac + lr1 * 128 + ((2 * q + 1) ^ r7b) * 16);
            a0 = cvt8(f0, f1);
            a1 = cvt8(f2, f3);
        }
#pragma unroll
        for (int ct = 0; ct < NCT; ++ct) {
            int col = ct * 16 + l15;
            int sb = q ^ (col & 3);
            short8 b = *(const short8*)(Bc + col * 64 + sb * 16);
            acc[0][ct] = __builtin_amdgcn_mfma_f32_16x16x32_bf16(a0, b, acc[0][ct], 0, 0, 0);
            acc[1][ct] = __builtin_amdgcn_mfma_f32_16x16x32_bf16(a1, b, acc[1][ct], 0, 0, 0);
        }
    };

    stage(0, 0);
    __syncthreads();
#pragma unroll 2
    for (int t = 0; t < NT - 1; ++t) {
        stage((t + 1) & 1, (t + 1) * 32);   // issue next-tile loads first
        compute(t & 1);                      // ds_read + MFMA current
        __syncthreads();                     // drains vmcnt (next tile ready)
    }
    compute((NT - 1) & 1);

    // epilogue: dinv scale + bf16 store
#pragma unroll
    for (int rt = 0; rt < 2; ++rt) {
#pragma unroll
        for (int reg = 0; reg < 4; ++reg) {
            int row = row0 + wv * 32 + rt * 16 + q * 4 + reg;
            if (row < N) {
                float sc = dinv[row];
#pragma unroll
                for (int ct = 0; ct < NCT; ++ct) {
                    out[(size_t)row * BN + ct * 16 + l15] = f2bf(acc[rt][ct][reg] * sc);
                }
            }
        }
    }
}

// ---------------- aggregation (bf16 in, fp32 accumulate) ----------------
__global__ __launch_bounds__(256) void agg1_kernel(
    const unsigned int* __restrict__ g1, const int* __restrict__ row_ptr,
    const int* __restrict__ csr_src, const float* __restrict__ dinv,
    const float* __restrict__ b1, unsigned int* __restrict__ h1) {
    int node = blockIdx.x * 4 + (threadIdx.x >> 6);
    int lane = threadIdx.x & 63;
    if (node >= N_NODES) return;
    unsigned u = g1[(size_t)node * 64 + lane];
    float a0 = lo_bf(u), a1 = hi_bf(u);
    int e = row_ptr[node], end = row_ptr[node + 1];
    for (; e + 4 <= end; e += 4) {
        int j0 = csr_src[e], j1 = csr_src[e + 1], j2 = csr_src[e + 2], j3 = csr_src[e + 3];
        unsigned u0 = g1[(size_t)j0 * 64 + lane];
        unsigned u1 = g1[(size_t)j1 * 64 + lane];
        unsigned u2 = g1[(size_t)j2 * 64 + lane];
        unsigned u3 = g1[(size_t)j3 * 64 + lane];
        a0 += lo_bf(u0) + lo_bf(u1) + lo_bf(u2) + lo_bf(u3);
        a1 += hi_bf(u0) + hi_bf(u1) + hi_bf(u2) + hi_bf(u3);
    }
    for (; e < end; ++e) {
        unsigned u0 = g1[(size_t)csr_src[e] * 64 + lane];
        a0 += lo_bf(u0);
        a1 += hi_bf(u0);
    }
    float d = dinv[node];
    float v0 = fmaxf(d * a0 + b1[2 * lane], 0.0f);
    float v1 = fmaxf(d * a1 + b1[2 * lane + 1], 0.0f);
    h1[(size_t)node * 64 + lane] = (unsigned)f2bf(v0) | ((unsigned)f2bf(v1) << 16);
}

__global__ __launch_bounds__(256) void agg2_lsm_kernel(
    const unsigned short* __restrict__ g2, const int* __restrict__ row_ptr,
    const int* __restrict__ csr_src, const float* __restrict__ dinv,
    const float* __restrict__ b2, float* __restrict__ out) {
    int node = blockIdx.x * 4 + (threadIdx.x >> 6);
    int lane = threadIdx.x & 63;
    if (node >= N_NODES) return;
    float a = bf2f(g2[(size_t)node * 64 + lane]);
    int e = row_ptr[node], end = row_ptr[node + 1];
    for (; e + 4 <= end; e += 4) {
        int j0 = csr_src[e], j1 = csr_src[e + 1], j2 = csr_src[e + 2], j3 = csr_src[e + 3];
        a += bf2f(g2[(size_t)j0 * 64 + lane]) + bf2f(g2[(size_t)j1 * 64 + lane]) +
             bf2f(g2[(size_t)j2 * 64 + lane]) + bf2f(g2[(size_t)j3 * 64 + lane]);
    }
    for (; e < end; ++e) a += bf2f(g2[(size_t)csr_src[e] * 64 + lane]);
    float v = dinv[node] * a + b2[lane];
    float m = v;
#pragma unroll
    for (int o = 32; o > 0; o >>= 1) m = fmaxf(m, __shfl_xor(m, o, 64));
    float ex = __expf(v - m);
    float s = ex;
#pragma unroll
    for (int o = 32; o > 0; o >>= 1) s += __shfl_xor(s, o, 64);
    out[(size_t)node * 64 + lane] = v - m - __logf(s);
}

// ---------------- launch ----------------

extern "C" void kernel_launch(void* const* d_in, const int* in_sizes, int n_in,
                              void* d_out, int out_size, void* d_ws, size_t ws_size,
                              hipStream_t stream) {
    const float* x  = (const float*)d_in[0];
    const int* eidx = (const int*)d_in[1];
    const float* W1 = (const float*)d_in[2];
    const float* b1 = (const float*)d_in[3];
    const float* W2 = (const float*)d_in[4];
    const float* b2 = (const float*)d_in[5];
    float* out = (float*)d_out;
    const int* src = eidx;
    const int* dst = eidx + N_EDGES;

    char* base = (char*)d_ws;
    size_t off = 0;
    auto alloc = [&](size_t bytes) -> void* {
        void* p = base + off;
        off += (bytes + 255) & ~(size_t)255;
        return p;
    };
    // zero-init region: [deg | gcur | ovcnt] — one memset
    int* zbase    = (int*)alloc((size_t)(N_NODES + NBUK + 64) * 4);
    int* deg      = zbase;
    int* gcur     = zbase + N_NODES;
    int* ovcnt    = zbase + N_NODES + NBUK;
    int* row_ptr  = (int*)alloc((size_t)(N_NODES + 1) * 4);
    int* cursor   = (int*)alloc((size_t)N_NODES * 4);
    float* dinv   = (float*)alloc((size_t)N_NODES * 4);
    int* bsum     = (int*)alloc((size_t)SCAN_NB * 4);
    unsigned* staging = (unsigned*)alloc((size_t)NBUK * SCAP * 4);   // 9.6 MB
    unsigned long long* ovbuf = (unsigned long long*)alloc((size_t)OV_CAP * 8);
    int* csr_src  = (int*)alloc((size_t)N_EDGES * 4);
    unsigned short* Wt1 = (unsigned short*)alloc((size_t)F_HID * F_IN * 2);
    unsigned short* Wt2 = (unsigned short*)alloc((size_t)F_OUT * F_HID * 2);
    unsigned short* g1  = (unsigned short*)alloc((size_t)N_NODES * F_HID * 2);
    unsigned short* h1  = (unsigned short*)alloc((size_t)N_NODES * F_HID * 2);
    unsigned short* g2  = g1;  // g1 dead after agg1

    hipMemsetAsync(zbase, 0, (size_t)(N_NODES + NBUK + 64) * 4, stream);
    partition_kernel<<<NBLK_A, 256, 0, stream>>>(src, dst, deg, staging, gcur, ovbuf, ovcnt);
    block_sum_kernel<<<SCAN_NB, 256, 0, stream>>>(deg, bsum, N_NODES);
    scan_partials_kernel<<<1, 512, 0, stream>>>(bsum, SCAN_NB);
    scan_final_kernel<<<SCAN_NB, 256, 0, stream>>>(deg, bsum, row_ptr, cursor, dinv, N_NODES);
    fill_kernel<<<NBUK, 256, 0, stream>>>(staging, gcur, cursor, csr_src, ovbuf, ovcnt);
    transpose_w_kernel<<<(F_HID * F_IN + F_OUT * F_HID + 255) / 256, 256, 0, stream>>>(
        W1, W2, Wt1, Wt2);

    int gblocks = (N_NODES + 127) / 128;  // 782
    gemm_lds_kernel<F_HID, F_IN, false><<<gblocks, 256, 0, stream>>>(
        (const void*)x, Wt1, dinv, g1, N_NODES);
    agg1_kernel<<<(N_NODES + 3) / 4, 256, 0, stream>>>(
        (const unsigned int*)g1, row_ptr, csr_src, dinv, b1, (unsigned int*)h1);

    gemm_lds_kernel<F_OUT, F_HID, true><<<gblocks, 256, 0, stream>>>(
        (const void*)h1, Wt2, dinv, g2, N_NODES);
    agg2_lsm_kernel<<<(N_NODES + 3) / 4, 256, 0, stream>>>(
        g2, row_ptr, csr_src, dinv, b2, out);
}

// Round 3
// 633.679 us; speedup vs baseline: 1.0483x; 1.0049x over previous
//
#include <hip/hip_runtime.h>
#include <cmath>

#define N_NODES 100000
#define N_EDGES 1600000
#define F_IN 512
#define F_HID 128
#define F_OUT 64

#define SCAN_NB ((N_NODES + 255) / 256)   // 391 blocks

// ---- bucketed CSR-build params ----
#define BK_SHIFT 10                        // 1024 nodes per bucket
#define NBUK ((N_NODES + 1023) >> 10)      // 98 buckets
#define SCAP 24576                         // staging capacity/bucket (mean 16327, +65 sigma)
#define LSLOT 64                           // LDS slots per bucket
#define NBLK_A 128                         // partition blocks
#define OV_CAP 4096                        // global overflow records

typedef __attribute__((ext_vector_type(8))) short short8;
typedef __attribute__((ext_vector_type(4))) float float4v;

// async global->LDS, 16B per lane; LDS dest is wave-uniform base + lane*16
#define GLOAD_LDS16(g, l)                                                      \
    __builtin_amdgcn_global_load_lds(                                          \
        (const __attribute__((address_space(1))) void*)(g),                    \
        (__attribute__((address_space(3))) void*)(l), 16, 0, 0)

__device__ __forceinline__ unsigned short f2bf(float f) {
    unsigned u = __builtin_bit_cast(unsigned, f);
    u += 0x7FFFu + ((u >> 16) & 1u);   // RNE
    return (unsigned short)(u >> 16);
}
__device__ __forceinline__ float bf2f(unsigned short s) {
    unsigned u = ((unsigned)s) << 16;
    return __builtin_bit_cast(float, u);
}
__device__ __forceinline__ float lo_bf(unsigned u) {
    return __builtin_bit_cast(float, u << 16);
}
__device__ __forceinline__ float hi_bf(unsigned u) {
    return __builtin_bit_cast(float, u & 0xFFFF0000u);
}
__device__ __forceinline__ short8 cvt8(float4 lo, float4 hi) {
    return short8{(short)f2bf(lo.x), (short)f2bf(lo.y), (short)f2bf(lo.z), (short)f2bf(lo.w),
                  (short)f2bf(hi.x), (short)f2bf(hi.y), (short)f2bf(hi.z), (short)f2bf(hi.w)};
}

// counted vmcnt wait (template-dispatched literal; asm needs an immediate)
template <int N>
__device__ __forceinline__ void waitvm() {
    if constexpr (N == 0) asm volatile("s_waitcnt vmcnt(0)" ::: "memory");
    else if constexpr (N == 3) asm volatile("s_waitcnt vmcnt(3)" ::: "memory");
    else if constexpr (N == 6) asm volatile("s_waitcnt vmcnt(6)" ::: "memory");
    else static_assert(N == 0 || N == 3 || N == 6, "add literal");
}
#define LGKM0() asm volatile("s_waitcnt lgkmcnt(0)" ::: "memory")
#define BAR() __builtin_amdgcn_s_barrier()
#define SCHED0() __builtin_amdgcn_sched_barrier(0)

// ---------------- partition: edges -> per-bucket staging (+deg count fused) ----------------
__global__ __launch_bounds__(256) void partition_kernel(
    const int* __restrict__ src, const int* __restrict__ dst,
    int* __restrict__ deg, unsigned* __restrict__ staging, int* __restrict__ gcur,
    unsigned long long* __restrict__ ovbuf, int* __restrict__ ovcnt) {
    __shared__ unsigned buf[NBUK][LSLOT];
    __shared__ int cnt[NBUK];
    int tid = threadIdx.x;
    for (int b = tid; b < NBUK; b += 256) cnt[b] = 0;
    __syncthreads();
    const int PER = (N_EDGES + NBLK_A - 1) / NBLK_A;   // 12500 (divisible by 4)
    int e0 = blockIdx.x * PER;
    int e1 = min(e0 + PER, N_EDGES);

    auto body = [&](int d, int s) {
        atomicAdd(&deg[d], 1);
        int b = d >> BK_SHIFT;
        unsigned rec = (unsigned)s | ((unsigned)(d & 1023) << 17);
        int slot = atomicAdd(&cnt[b], 1);
        if (slot < LSLOT) {
            buf[b][slot] = rec;
        } else {  // rare LDS overflow: spill (src,dst) to global list
            int op = atomicAdd(ovcnt, 1);
            if (op < OV_CAP)
                ovbuf[op] = ((unsigned long long)(unsigned)d << 32) | (unsigned)s;
        }
    };
    auto drain = [&](void) {
        for (int b = tid; b < NBUK; b += 256) {
            int c = min(cnt[b], LSLOT);
            int full = c & ~15;
            if (full > 0) {
                int pos = atomicAdd(&gcur[b], full);
                if (pos + full <= SCAP) {
                    unsigned* dp = &staging[(size_t)b * SCAP + pos];
                    for (int i = 0; i < full; ++i) dp[i] = buf[b][i];
                }
                for (int i = 0; i < c - full; ++i) buf[b][i] = buf[b][full + i];
            }
            cnt[b] = c - full;
        }
    };

    int base = e0;
    for (; base + 1024 <= e1; base += 1024) {
        int e = base + tid * 4;
        int4 dv = *(const int4*)(dst + e);   // 16B vectorized edge loads
        int4 sv = *(const int4*)(src + e);
        body(dv.x, sv.x);
        body(dv.y, sv.y);
        body(dv.z, sv.z);
        body(dv.w, sv.w);
        __syncthreads();
        drain();
        __syncthreads();
    }
    // tail (<1024 edges), scalar
    for (int e = base + tid; e < e1; e += 256) body(dst[e], src[e]);
    __syncthreads();
    drain();
    __syncthreads();
    // final flush of remainders
    for (int b = tid; b < NBUK; b += 256) {
        int c = cnt[b];
        if (c > 0) {
            int pos = atomicAdd(&gcur[b], c);
            if (pos + c <= SCAP)
                for (int i = 0; i < c; ++i) staging[(size_t)b * SCAP + pos + i] = buf[b][i];
        }
    }
}

// ---------------- fill: one block per bucket -> single-XCD-local CSR scatter ----------------
__global__ __launch_bounds__(256) void fill_kernel(
    const unsigned* __restrict__ staging, const int* __restrict__ gcur,
    int* __restrict__ cursor, int* __restrict__ csr_src,
    const unsigned long long* __restrict__ ovbuf, const int* __restrict__ ovcnt) {
    int b = blockIdx.x;
    int node0 = b << BK_SHIFT;
    int n = gcur[b];
    if (n > SCAP) n = SCAP;
    const unsigned* sp = &staging[(size_t)b * SCAP];
    for (int i = threadIdx.x; i < n; i += 256) {
        unsigned rec = sp[i];
        int s = (int)(rec & 0x1FFFFu);
        int d = node0 + (int)(rec >> 17);
        int pos = atomicAdd(&cursor[d], 1);
        csr_src[pos] = s;
    }
    int oc = *ovcnt;
    if (oc > OV_CAP) oc = OV_CAP;
    for (int i = threadIdx.x; i < oc; i += 256) {
        unsigned long long r = ovbuf[i];
        int d = (int)(r >> 32);
        if ((d >> BK_SHIFT) == b) {
            int pos = atomicAdd(&cursor[d], 1);
            csr_src[pos] = (int)(r & 0xffffffffu);
        }
    }
}

// ---------------- scans ----------------

__global__ __launch_bounds__(256) void block_sum_kernel(const int* __restrict__ deg,
                                                        int* __restrict__ bsum, int n) {
    int g = blockIdx.x * 256 + threadIdx.x;
    int v = (g < n) ? deg[g] : 0;
    __shared__ int ws[4];
    int lane = threadIdx.x & 63;
    int w = threadIdx.x >> 6;
#pragma unroll
    for (int o = 32; o > 0; o >>= 1) v += __shfl_down(v, o, 64);
    if (lane == 0) ws[w] = v;
    __syncthreads();
    if (threadIdx.x == 0) bsum[blockIdx.x] = ws[0] + ws[1] + ws[2] + ws[3];
}

__global__ __launch_bounds__(512) void scan_partials_kernel(int* __restrict__ bsum, int nb) {
    __shared__ int t[512];
    int tid = threadIdx.x;
    int v = (tid < nb) ? bsum[tid] : 0;
    t[tid] = v;
    __syncthreads();
    for (int d = 1; d < 512; d <<= 1) {
        int u = (tid >= d) ? t[tid - d] : 0;
        __syncthreads();
        t[tid] += u;
        __syncthreads();
    }
    if (tid < nb) bsum[tid] = t[tid] - v;  // exclusive
}

__global__ __launch_bounds__(256) void scan_final_kernel(const int* __restrict__ deg,
                                                         const int* __restrict__ bsum,
                                                         int* __restrict__ row_ptr,
                                                         int* __restrict__ cursor,
                                                         float* __restrict__ dinv, int n) {
    __shared__ int t[256];
    int g = blockIdx.x * 256 + threadIdx.x;
    int tid = threadIdx.x;
    int v = (g < n) ? deg[g] : 0;
    t[tid] = v;
    __syncthreads();
    for (int d = 1; d < 256; d <<= 1) {
        int u = (tid >= d) ? t[tid - d] : 0;
        __syncthreads();
        t[tid] += u;
        __syncthreads();
    }
    int off = bsum[blockIdx.x] + t[tid] - v;
    if (g < n) {
        row_ptr[g] = off;
        cursor[g] = off;
        dinv[g] = rsqrtf((float)(v + 1));
    }
    if (g == n - 1) row_ptr[n] = off + v;
}

// ---------------- W transpose+convert: Wt[n][k] bf16 ----------------

__global__ void transpose_w_kernel(const float* __restrict__ W1, const float* __restrict__ W2,
                                   unsigned short* __restrict__ Wt1,
                                   unsigned short* __restrict__ Wt2) {
    int g = blockIdx.x * 256 + threadIdx.x;
    if (g < F_HID * F_IN) {               // Wt1: [128][512]
        int n = g >> 9, k = g & 511;
        Wt1[g] = f2bf(W1[k * F_HID + n]);
    } else {
        int h = g - F_HID * F_IN;         // Wt2: [64][128]
        if (h < F_OUT * F_HID) {
            int n = h >> 7, k = h & 127;
            Wt2[h] = f2bf(W2[k * F_OUT + n]);
        }
    }
}

// ---------------- LDS-staged MFMA GEMM, counted-vmcnt pipeline (T3+T4) ----------------
// R7: R6's __syncthreads per k-step emitted s_waitcnt vmcnt(0) -> drained the
// 6 just-issued global_load_lds (~600-900cyc) every step with only ~300cyc of
// compute to hide it (drain-0 antipattern, m218). Now: counted vmcnt(SL),
// raw s_barrier, loads span barriers; steady state never drains to 0.
// Per step: waitvm<SL> (stage t done, stage t+1 in flight) -> barrier ->
// compute(t) -> lgkmcnt(0) -> barrier -> stage tile t+2 into buffer t&1.
// Swizzle unchanged (both-sides rule #21): linear LDS dest, XOR'd source slot,
// same XOR on ds_read.

template <int BN, int K, bool A_BF16>
__global__ __launch_bounds__(256, 3) void gemm_lds_kernel(
    const void* __restrict__ Araw, const unsigned short* __restrict__ Wt,
    const float* __restrict__ dinv, unsigned short* __restrict__ out, int N) {
    constexpr int NCT = BN / 16;
    constexpr int AE = A_BF16 ? 2 : 4;         // A element bytes
    constexpr int SLOTS_A = (32 * AE) / 16;    // 16B slots per row per 32-k chunk (4 or 8)
    constexpr int MA = SLOTS_A - 1;
    constexpr int ABYTES = 128 * 32 * AE;      // per A buffer (8K or 16K)
    constexpr int BBYTES = BN * 32 * 2;        // per B buffer (4K or 8K)
    constexpr int NT = K / 32;
    constexpr int SL = (128 * SLOTS_A + BN * 4) / 256;  // gload_lds per stage: 6 (gemm1) / 3 (gemm2)

    __shared__ __align__(128) char Abuf[2][ABYTES];
    __shared__ __align__(128) char Bbuf[2][BBYTES];

    const char* Ab = (const char*)Araw;
    const char* Bb = (const char*)Wt;
    int tid = threadIdx.x;
    int lane = tid & 63;
    int wv = tid >> 6;
    int row0 = blockIdx.x * 128;
    int l15 = lane & 15;
    int q = lane >> 4;

    float4v acc[2][NCT] = {};

    auto stage = [&](int buf, int k0) {
        // A: 128 rows x 32 elems, 16B chunks; chunk c -> row c/SLOTS_A, slot c%SLOTS_A
        constexpr int CA = 128 * SLOTS_A;
#pragma unroll
        for (int i = 0; i < CA / 256; ++i) {
            int c = i * 256 + tid;
            int cw = i * 256 + (tid & ~63);      // wave-uniform chunk base
            int row = c / SLOTS_A;
            int s = c & MA;
            int g = s ^ (row & MA);              // inverse swizzle on SOURCE
            int rg = row0 + row;
            if (rg >= N) rg = N - 1;             // clamp (last block tail)
            GLOAD_LDS16(Ab + ((size_t)rg * K + k0) * AE + g * 16,
                        &Abuf[buf][cw * 16]);
        }
        // B: BN cols x 32 k bf16 (64B per col = 4 slots)
        constexpr int CB = BN * 4;
#pragma unroll
        for (int i = 0; i < CB / 256; ++i) {
            int c = i * 256 + tid;
            int cw = i * 256 + (tid & ~63);
            int col = c >> 2;
            int s = c & 3;
            int g = s ^ (col & 3);
            GLOAD_LDS16(Bb + ((size_t)col * K + k0) * 2 + g * 16,
                        &Bbuf[buf][cw * 16]);
        }
    };

    auto compute = [&](int buf) {
        const char* Ac = Abuf[buf];
        const char* Bc = Bbuf[buf];
        int lr0 = wv * 32 + l15;
        int lr1 = lr0 + 16;
        short8 a0, a1;
        if constexpr (A_BF16) {
            int s0 = q ^ (lr0 & 3);
            int s1 = q ^ (lr1 & 3);
            a0 = *(const short8*)(Ac + lr0 * 64 + s0 * 16);
            a1 = *(const short8*)(Ac + lr1 * 64 + s1 * 16);
        } else {
            int r7a = lr0 & 7, r7b = lr1 & 7;
            float4 f0 = *(const float4*)(Ac + lr0 * 128 + ((2 * q) ^ r7a) * 16);
            float4 f1 = *(const float4*)(Ac + lr0 * 128 + ((2 * q + 1) ^ r7a) * 16);
            float4 f2 = *(const float4*)(Ac + lr1 * 128 + ((2 * q) ^ r7b) * 16);
            float4 f3 = *(const float4*)(Ac + lr1 * 128 + ((2 * q + 1) ^ r7b) * 16);
            a0 = cvt8(f0, f1);
            a1 = cvt8(f2, f3);
        }
#pragma unroll
        for (int ct = 0; ct < NCT; ++ct) {
            int col = ct * 16 + l15;
            int sb = q ^ (col & 3);
            short8 b = *(const short8*)(Bc + col * 64 + sb * 16);
            acc[0][ct] = __builtin_amdgcn_mfma_f32_16x16x32_bf16(a0, b, acc[0][ct], 0, 0, 0);
            acc[1][ct] = __builtin_amdgcn_mfma_f32_16x16x32_bf16(a1, b, acc[1][ct], 0, 0, 0);
        }
    };

    // prologue: 2 tiles in flight (2*SL loads outstanding)
    stage(0, 0);
    stage(1, 32);
#pragma unroll 1
    for (int t = 0; t < NT - 2; ++t) {
        waitvm<SL>();                 // stage(t) landed; stage(t+1) stays in flight
        BAR();
        SCHED0();
        compute(t & 1);
        LGKM0();                      // all ds_reads of buf t&1 executed
        BAR();
        SCHED0();
        stage(t & 1, (t + 2) * 32);   // overwrite consumed buffer with tile t+2
    }
    // tile NT-2 (stage NT-1 still in flight)
    waitvm<SL>();
    BAR();
    SCHED0();
    compute((NT - 2) & 1);
    // tile NT-1 (final drain)
    waitvm<0>();
    BAR();
    SCHED0();
    compute((NT - 1) & 1);

    // epilogue: dinv scale + bf16 store
#pragma unroll
    for (int rt = 0; rt < 2; ++rt) {
#pragma unroll
        for (int reg = 0; reg < 4; ++reg) {
            int row = row0 + wv * 32 + rt * 16 + q * 4 + reg;
            if (row < N) {
                float sc = dinv[row];
#pragma unroll
                for (int ct = 0; ct < NCT; ++ct) {
                    out[(size_t)row * BN + ct * 16 + l15] = f2bf(acc[rt][ct][reg] * sc);
                }
            }
        }
    }
}

// ---------------- aggregation (bf16 in, fp32 accumulate) ----------------
__global__ __launch_bounds__(256) void agg1_kernel(
    const unsigned int* __restrict__ g1, const int* __restrict__ row_ptr,
    const int* __restrict__ csr_src, const float* __restrict__ dinv,
    const float* __restrict__ b1, unsigned int* __restrict__ h1) {
    int node = blockIdx.x * 4 + (threadIdx.x >> 6);
    int lane = threadIdx.x & 63;
    if (node >= N_NODES) return;
    unsigned u = g1[(size_t)node * 64 + lane];
    float a0 = lo_bf(u), a1 = hi_bf(u);
    int e = row_ptr[node], end = row_ptr[node + 1];
    for (; e + 4 <= end; e += 4) {
        int j0 = csr_src[e], j1 = csr_src[e + 1], j2 = csr_src[e + 2], j3 = csr_src[e + 3];
        unsigned u0 = g1[(size_t)j0 * 64 + lane];
        unsigned u1 = g1[(size_t)j1 * 64 + lane];
        unsigned u2 = g1[(size_t)j2 * 64 + lane];
        unsigned u3 = g1[(size_t)j3 * 64 + lane];
        a0 += lo_bf(u0) + lo_bf(u1) + lo_bf(u2) + lo_bf(u3);
        a1 += hi_bf(u0) + hi_bf(u1) + hi_bf(u2) + hi_bf(u3);
    }
    for (; e < end; ++e) {
        unsigned u0 = g1[(size_t)csr_src[e] * 64 + lane];
        a0 += lo_bf(u0);
        a1 += hi_bf(u0);
    }
    float d = dinv[node];
    float v0 = fmaxf(d * a0 + b1[2 * lane], 0.0f);
    float v1 = fmaxf(d * a1 + b1[2 * lane + 1], 0.0f);
    h1[(size_t)node * 64 + lane] = (unsigned)f2bf(v0) | ((unsigned)f2bf(v1) << 16);
}

__global__ __launch_bounds__(256) void agg2_lsm_kernel(
    const unsigned short* __restrict__ g2, const int* __restrict__ row_ptr,
    const int* __restrict__ csr_src, const float* __restrict__ dinv,
    const float* __restrict__ b2, float* __restrict__ out) {
    int node = blockIdx.x * 4 + (threadIdx.x >> 6);
    int lane = threadIdx.x & 63;
    if (node >= N_NODES) return;
    float a = bf2f(g2[(size_t)node * 64 + lane]);
    int e = row_ptr[node], end = row_ptr[node + 1];
    for (; e + 4 <= end; e += 4) {
        int j0 = csr_src[e], j1 = csr_src[e + 1], j2 = csr_src[e + 2], j3 = csr_src[e + 3];
        a += bf2f(g2[(size_t)j0 * 64 + lane]) + bf2f(g2[(size_t)j1 * 64 + lane]) +
             bf2f(g2[(size_t)j2 * 64 + lane]) + bf2f(g2[(size_t)j3 * 64 + lane]);
    }
    for (; e < end; ++e) a += bf2f(g2[(size_t)csr_src[e] * 64 + lane]);
    float v = dinv[node] * a + b2[lane];
    float m = v;
#pragma unroll
    for (int o = 32; o > 0; o >>= 1) m = fmaxf(m, __shfl_xor(m, o, 64));
    float ex = __expf(v - m);
    float s = ex;
#pragma unroll
    for (int o = 32; o > 0; o >>= 1) s += __shfl_xor(s, o, 64);
    out[(size_t)node * 64 + lane] = v - m - __logf(s);
}

// ---------------- launch ----------------

extern "C" void kernel_launch(void* const* d_in, const int* in_sizes, int n_in,
                              void* d_out, int out_size, void* d_ws, size_t ws_size,
                              hipStream_t stream) {
    const float* x  = (const float*)d_in[0];
    const int* eidx = (const int*)d_in[1];
    const float* W1 = (const float*)d_in[2];
    const float* b1 = (const float*)d_in[3];
    const float* W2 = (const float*)d_in[4];
    const float* b2 = (const float*)d_in[5];
    float* out = (float*)d_out;
    const int* src = eidx;
    const int* dst = eidx + N_EDGES;

    char* base = (char*)d_ws;
    size_t off = 0;
    auto alloc = [&](size_t bytes) -> void* {
        void* p = base + off;
        off += (bytes + 255) & ~(size_t)255;
        return p;
    };
    // zero-init region: [deg | gcur | ovcnt] — one memset
    int* zbase    = (int*)alloc((size_t)(N_NODES + NBUK + 64) * 4);
    int* deg      = zbase;
    int* gcur     = zbase + N_NODES;
    int* ovcnt    = zbase + N_NODES + NBUK;
    int* row_ptr  = (int*)alloc((size_t)(N_NODES + 1) * 4);
    int* cursor   = (int*)alloc((size_t)N_NODES * 4);
    float* dinv   = (float*)alloc((size_t)N_NODES * 4);
    int* bsum     = (int*)alloc((size_t)SCAN_NB * 4);
    unsigned* staging = (unsigned*)alloc((size_t)NBUK * SCAP * 4);   // 9.6 MB
    unsigned long long* ovbuf = (unsigned long long*)alloc((size_t)OV_CAP * 8);
    int* csr_src  = (int*)alloc((size_t)N_EDGES * 4);
    unsigned short* Wt1 = (unsigned short*)alloc((size_t)F_HID * F_IN * 2);
    unsigned short* Wt2 = (unsigned short*)alloc((size_t)F_OUT * F_HID * 2);
    unsigned short* g1  = (unsigned short*)alloc((size_t)N_NODES * F_HID * 2);
    unsigned short* h1  = (unsigned short*)alloc((size_t)N_NODES * F_HID * 2);
    unsigned short* g2  = g1;  // g1 dead after agg1

    hipMemsetAsync(zbase, 0, (size_t)(N_NODES + NBUK + 64) * 4, stream);
    partition_kernel<<<NBLK_A, 256, 0, stream>>>(src, dst, deg, staging, gcur, ovbuf, ovcnt);
    block_sum_kernel<<<SCAN_NB, 256, 0, stream>>>(deg, bsum, N_NODES);
    scan_partials_kernel<<<1, 512, 0, stream>>>(bsum, SCAN_NB);
    scan_final_kernel<<<SCAN_NB, 256, 0, stream>>>(deg, bsum, row_ptr, cursor, dinv, N_NODES);
    fill_kernel<<<NBUK, 256, 0, stream>>>(staging, gcur, cursor, csr_src, ovbuf, ovcnt);
    transpose_w_kernel<<<(F_HID * F_IN + F_OUT * F_HID + 255) / 256, 256, 0, stream>>>(
        W1, W2, Wt1, Wt2);

    int gblocks = (N_NODES + 127) / 128;  // 782
    gemm_lds_kernel<F_HID, F_IN, false><<<gblocks, 256, 0, stream>>>(
        (const void*)x, Wt1, dinv, g1, N_NODES);
    agg1_kernel<<<(N_NODES + 3) / 4, 256, 0, stream>>>(
        (const unsigned int*)g1, row_ptr, csr_src, dinv, b1, (unsigned int*)h1);

    gemm_lds_kernel<F_OUT, F_HID, true><<<gblocks, 256, 0, stream>>>(
        (const void*)h1, Wt2, dinv, g2, N_NODES);
    agg2_lsm_kernel<<<(N_NODES + 3) / 4, 256, 0, stream>>>(
        g2, row_ptr, csr_src, dinv, b2, out);
}

// Round 5
// 594.656 us; speedup vs baseline: 1.1171x; 1.0656x over previous
//
#include <hip/hip_runtime.h>
#include <cmath>

#define N_NODES 100000
#define N_EDGES 1600000
#define F_IN 512
#define F_HID 128
#define F_OUT 64

#define SCAN_NB ((N_NODES + 255) / 256)   // 391 blocks

// ---- bucketed CSR-build params ----
#define BK_SHIFT 10                        // 1024 nodes per bucket
#define NBUK ((N_NODES + 1023) >> 10)      // 98 buckets
#define SCAP 24576                         // staging capacity/bucket (mean 16327, +65 sigma)
#define LSLOT 64                           // LDS slots per bucket
#define NBLK_A 128                         // partition blocks
#define OV_CAP 4096                        // global overflow records

typedef __attribute__((ext_vector_type(8))) short short8;
typedef __attribute__((ext_vector_type(4))) float float4v;

// async global->LDS, 16B per lane; LDS dest is wave-uniform base + lane*16
#define GLOAD_LDS16(g, l)                                                      \
    __builtin_amdgcn_global_load_lds(                                          \
        (const __attribute__((address_space(1))) void*)(g),                    \
        (__attribute__((address_space(3))) void*)(l), 16, 0, 0)

__device__ __forceinline__ unsigned short f2bf(float f) {
    unsigned u = __builtin_bit_cast(unsigned, f);
    u += 0x7FFFu + ((u >> 16) & 1u);   // RNE
    return (unsigned short)(u >> 16);
}
__device__ __forceinline__ float bf2f(unsigned short s) {
    unsigned u = ((unsigned)s) << 16;
    return __builtin_bit_cast(float, u);
}
__device__ __forceinline__ float lo_bf(unsigned u) {
    return __builtin_bit_cast(float, u << 16);
}
__device__ __forceinline__ float hi_bf(unsigned u) {
    return __builtin_bit_cast(float, u & 0xFFFF0000u);
}
__device__ __forceinline__ short8 cvt8(float4 lo, float4 hi) {
    return short8{(short)f2bf(lo.x), (short)f2bf(lo.y), (short)f2bf(lo.z), (short)f2bf(lo.w),
                  (short)f2bf(hi.x), (short)f2bf(hi.y), (short)f2bf(hi.z), (short)f2bf(hi.w)};
}
__device__ __forceinline__ unsigned pack_bf2(float a, float b) {
    return (unsigned)f2bf(a) | ((unsigned)f2bf(b) << 16);
}

// counted vmcnt wait (template-dispatched literal; asm needs an immediate)
template <int N>
__device__ __forceinline__ void waitvm() {
    if constexpr (N == 0) asm volatile("s_waitcnt vmcnt(0)" ::: "memory");
    else if constexpr (N == 3) asm volatile("s_waitcnt vmcnt(3)" ::: "memory");
    else if constexpr (N == 6) asm volatile("s_waitcnt vmcnt(6)" ::: "memory");
    else static_assert(N == 0 || N == 3 || N == 6, "add literal");
}
#define LGKM0() asm volatile("s_waitcnt lgkmcnt(0)" ::: "memory")
#define BAR() __builtin_amdgcn_s_barrier()
#define SCHED0() __builtin_amdgcn_sched_barrier(0)

// ---------------- partition: edges -> per-bucket staging (+deg count fused) ----------------
__global__ __launch_bounds__(256) void partition_kernel(
    const int* __restrict__ src, const int* __restrict__ dst,
    int* __restrict__ deg, unsigned* __restrict__ staging, int* __restrict__ gcur,
    unsigned long long* __restrict__ ovbuf, int* __restrict__ ovcnt) {
    __shared__ unsigned buf[NBUK][LSLOT];
    __shared__ int cnt[NBUK];
    int tid = threadIdx.x;
    for (int b = tid; b < NBUK; b += 256) cnt[b] = 0;
    __syncthreads();
    const int PER = (N_EDGES + NBLK_A - 1) / NBLK_A;   // 12500 (divisible by 4)
    int e0 = blockIdx.x * PER;
    int e1 = min(e0 + PER, N_EDGES);

    auto body = [&](int d, int s) {
        atomicAdd(&deg[d], 1);
        int b = d >> BK_SHIFT;
        unsigned rec = (unsigned)s | ((unsigned)(d & 1023) << 17);
        int slot = atomicAdd(&cnt[b], 1);
        if (slot < LSLOT) {
            buf[b][slot] = rec;
        } else {  // rare LDS overflow: spill (src,dst) to global list
            int op = atomicAdd(ovcnt, 1);
            if (op < OV_CAP)
                ovbuf[op] = ((unsigned long long)(unsigned)d << 32) | (unsigned)s;
        }
    };
    auto drain = [&](void) {
        for (int b = tid; b < NBUK; b += 256) {
            int c = min(cnt[b], LSLOT);
            int full = c & ~15;
            if (full > 0) {
                int pos = atomicAdd(&gcur[b], full);
                if (pos + full <= SCAP) {
                    unsigned* dp = &staging[(size_t)b * SCAP + pos];
                    for (int i = 0; i < full; ++i) dp[i] = buf[b][i];
                }
                for (int i = 0; i < c - full; ++i) buf[b][i] = buf[b][full + i];
            }
            cnt[b] = c - full;
        }
    };

    int base = e0;
    for (; base + 1024 <= e1; base += 1024) {
        int e = base + tid * 4;
        int4 dv = *(const int4*)(dst + e);   // 16B vectorized edge loads
        int4 sv = *(const int4*)(src + e);
        body(dv.x, sv.x);
        body(dv.y, sv.y);
        body(dv.z, sv.z);
        body(dv.w, sv.w);
        __syncthreads();
        drain();
        __syncthreads();
    }
    // tail (<1024 edges), scalar
    for (int e = base + tid; e < e1; e += 256) body(dst[e], src[e]);
    __syncthreads();
    drain();
    __syncthreads();
    // final flush of remainders
    for (int b = tid; b < NBUK; b += 256) {
        int c = cnt[b];
        if (c > 0) {
            int pos = atomicAdd(&gcur[b], c);
            if (pos + c <= SCAP)
                for (int i = 0; i < c; ++i) staging[(size_t)b * SCAP + pos + i] = buf[b][i];
        }
    }
}

// ---------------- fill: one block per bucket -> single-XCD-local CSR scatter ----------------
__global__ __launch_bounds__(256) void fill_kernel(
    const unsigned* __restrict__ staging, const int* __restrict__ gcur,
    int* __restrict__ cursor, int* __restrict__ csr_src,
    const unsigned long long* __restrict__ ovbuf, const int* __restrict__ ovcnt) {
    int b = blockIdx.x;
    int node0 = b << BK_SHIFT;
    int n = gcur[b];
    if (n > SCAP) n = SCAP;
    const unsigned* sp = &staging[(size_t)b * SCAP];
    for (int i = threadIdx.x; i < n; i += 256) {
        unsigned rec = sp[i];
        int s = (int)(rec & 0x1FFFFu);
        int d = node0 + (int)(rec >> 17);
        int pos = atomicAdd(&cursor[d], 1);
        csr_src[pos] = s;
    }
    int oc = *ovcnt;
    if (oc > OV_CAP) oc = OV_CAP;
    for (int i = threadIdx.x; i < oc; i += 256) {
        unsigned long long r = ovbuf[i];
        int d = (int)(r >> 32);
        if ((d >> BK_SHIFT) == b) {
            int pos = atomicAdd(&cursor[d], 1);
            csr_src[pos] = (int)(r & 0xffffffffu);
        }
    }
}

// ---------------- scans ----------------

__global__ __launch_bounds__(256) void block_sum_kernel(const int* __restrict__ deg,
                                                        int* __restrict__ bsum, int n) {
    int g = blockIdx.x * 256 + threadIdx.x;
    int v = (g < n) ? deg[g] : 0;
    __shared__ int ws[4];
    int lane = threadIdx.x & 63;
    int w = threadIdx.x >> 6;
#pragma unroll
    for (int o = 32; o > 0; o >>= 1) v += __shfl_down(v, o, 64);
    if (lane == 0) ws[w] = v;
    __syncthreads();
    if (threadIdx.x == 0) bsum[blockIdx.x] = ws[0] + ws[1] + ws[2] + ws[3];
}

__global__ __launch_bounds__(512) void scan_partials_kernel(int* __restrict__ bsum, int nb) {
    __shared__ int t[512];
    int tid = threadIdx.x;
    int v = (tid < nb) ? bsum[tid] : 0;
    t[tid] = v;
    __syncthreads();
    for (int d = 1; d < 512; d <<= 1) {
        int u = (tid >= d) ? t[tid - d] : 0;
        __syncthreads();
        t[tid] += u;
        __syncthreads();
    }
    if (tid < nb) bsum[tid] = t[tid] - v;  // exclusive
}

__global__ __launch_bounds__(256) void scan_final_kernel(const int* __restrict__ deg,
                                                         const int* __restrict__ bsum,
                                                         int* __restrict__ row_ptr,
                                                         int* __restrict__ cursor,
                                                         float* __restrict__ dinv, int n) {
    __shared__ int t[256];
    int g = blockIdx.x * 256 + threadIdx.x;
    int tid = threadIdx.x;
    int v = (g < n) ? deg[g] : 0;
    t[tid] = v;
    __syncthreads();
    for (int d = 1; d < 256; d <<= 1) {
        int u = (tid >= d) ? t[tid - d] : 0;
        __syncthreads();
        t[tid] += u;
        __syncthreads();
    }
    int off = bsum[blockIdx.x] + t[tid] - v;
    if (g < n) {
        row_ptr[g] = off;
        cursor[g] = off;
        dinv[g] = rsqrtf((float)(v + 1));
    }
    if (g == n - 1) row_ptr[n] = off + v;
}

// ---------------- W transpose+convert: Wt[n][k] bf16 ----------------

__global__ void transpose_w_kernel(const float* __restrict__ W1, const float* __restrict__ W2,
                                   unsigned short* __restrict__ Wt1,
                                   unsigned short* __restrict__ Wt2) {
    int g = blockIdx.x * 256 + threadIdx.x;
    if (g < F_HID * F_IN) {               // Wt1: [128][512]
        int n = g >> 9, k = g & 511;
        Wt1[g] = f2bf(W1[k * F_HID + n]);
    } else {
        int h = g - F_HID * F_IN;         // Wt2: [64][128]
        if (h < F_OUT * F_HID) {
            int n = h >> 7, k = h & 127;
            Wt2[h] = f2bf(W2[k * F_OUT + n]);
        }
    }
}

// ---------------- LDS-staged MFMA GEMM, counted-vmcnt pipeline (T3+T4) ----------------

template <int BN, int K, bool A_BF16>
__global__ __launch_bounds__(256, 3) void gemm_lds_kernel(
    const void* __restrict__ Araw, const unsigned short* __restrict__ Wt,
    const float* __restrict__ dinv, unsigned short* __restrict__ out, int N) {
    constexpr int NCT = BN / 16;
    constexpr int AE = A_BF16 ? 2 : 4;         // A element bytes
    constexpr int SLOTS_A = (32 * AE) / 16;    // 16B slots per row per 32-k chunk (4 or 8)
    constexpr int MA = SLOTS_A - 1;
    constexpr int ABYTES = 128 * 32 * AE;      // per A buffer (8K or 16K)
    constexpr int BBYTES = BN * 32 * 2;        // per B buffer (4K or 8K)
    constexpr int NT = K / 32;
    constexpr int SL = (128 * SLOTS_A + BN * 4) / 256;  // gload_lds per stage: 6 (gemm1) / 3 (gemm2)

    __shared__ __align__(128) char Abuf[2][ABYTES];
    __shared__ __align__(128) char Bbuf[2][BBYTES];

    const char* Ab = (const char*)Araw;
    const char* Bb = (const char*)Wt;
    int tid = threadIdx.x;
    int lane = tid & 63;
    int wv = tid >> 6;
    int row0 = blockIdx.x * 128;
    int l15 = lane & 15;
    int q = lane >> 4;

    float4v acc[2][NCT] = {};

    auto stage = [&](int buf, int k0) {
        // A: 128 rows x 32 elems, 16B chunks; chunk c -> row c/SLOTS_A, slot c%SLOTS_A
        constexpr int CA = 128 * SLOTS_A;
#pragma unroll
        for (int i = 0; i < CA / 256; ++i) {
            int c = i * 256 + tid;
            int cw = i * 256 + (tid & ~63);      // wave-uniform chunk base
            int row = c / SLOTS_A;
            int s = c & MA;
            int g = s ^ (row & MA);              // inverse swizzle on SOURCE
            int rg = row0 + row;
            if (rg >= N) rg = N - 1;             // clamp (last block tail)
            GLOAD_LDS16(Ab + ((size_t)rg * K + k0) * AE + g * 16,
                        &Abuf[buf][cw * 16]);
        }
        // B: BN cols x 32 k bf16 (64B per col = 4 slots)
        constexpr int CB = BN * 4;
#pragma unroll
        for (int i = 0; i < CB / 256; ++i) {
            int c = i * 256 + tid;
            int cw = i * 256 + (tid & ~63);
            int col = c >> 2;
            int s = c & 3;
            int g = s ^ (col & 3);
            GLOAD_LDS16(Bb + ((size_t)col * K + k0) * 2 + g * 16,
                        &Bbuf[buf][cw * 16]);
        }
    };

    auto compute = [&](int buf) {
        const char* Ac = Abuf[buf];
        const char* Bc = Bbuf[buf];
        int lr0 = wv * 32 + l15;
        int lr1 = lr0 + 16;
        short8 a0, a1;
        if constexpr (A_BF16) {
            int s0 = q ^ (lr0 & 3);
            int s1 = q ^ (lr1 & 3);
            a0 = *(const short8*)(Ac + lr0 * 64 + s0 * 16);
            a1 = *(const short8*)(Ac + lr1 * 64 + s1 * 16);
        } else {
            int r7a = lr0 & 7, r7b = lr1 & 7;
            float4 f0 = *(const float4*)(Ac + lr0 * 128 + ((2 * q) ^ r7a) * 16);
            float4 f1 = *(const float4*)(Ac + lr0 * 128 + ((2 * q + 1) ^ r7a) * 16);
            float4 f2 = *(const float4*)(Ac + lr1 * 128 + ((2 * q) ^ r7b) * 16);
            float4 f3 = *(const float4*)(Ac + lr1 * 128 + ((2 * q + 1) ^ r7b) * 16);
            a0 = cvt8(f0, f1);
            a1 = cvt8(f2, f3);
        }
#pragma unroll
        for (int ct = 0; ct < NCT; ++ct) {
            int col = ct * 16 + l15;
            int sb = q ^ (col & 3);
            short8 b = *(const short8*)(Bc + col * 64 + sb * 16);
            acc[0][ct] = __builtin_amdgcn_mfma_f32_16x16x32_bf16(a0, b, acc[0][ct], 0, 0, 0);
            acc[1][ct] = __builtin_amdgcn_mfma_f32_16x16x32_bf16(a1, b, acc[1][ct], 0, 0, 0);
        }
    };

    // prologue: 2 tiles in flight (2*SL loads outstanding)
    stage(0, 0);
    stage(1, 32);
#pragma unroll 1
    for (int t = 0; t < NT - 2; ++t) {
        waitvm<SL>();                 // stage(t) landed; stage(t+1) stays in flight
        BAR();
        SCHED0();
        compute(t & 1);
        LGKM0();                      // all ds_reads of buf t&1 executed
        BAR();
        SCHED0();
        stage(t & 1, (t + 2) * 32);   // overwrite consumed buffer with tile t+2
    }
    // tile NT-2 (stage NT-1 still in flight)
    waitvm<SL>();
    BAR();
    SCHED0();
    compute((NT - 2) & 1);
    // tile NT-1 (final drain)
    waitvm<0>();
    BAR();
    SCHED0();
    compute((NT - 1) & 1);

    // epilogue: dinv scale + bf16 store
#pragma unroll
    for (int rt = 0; rt < 2; ++rt) {
#pragma unroll
        for (int reg = 0; reg < 4; ++reg) {
            int row = row0 + wv * 32 + rt * 16 + q * 4 + reg;
            if (row < N) {
                float sc = dinv[row];
#pragma unroll
                for (int ct = 0; ct < NCT; ++ct) {
                    out[(size_t)row * BN + ct * 16 + l15] = f2bf(acc[rt][ct][reg] * sc);
                }
            }
        }
    }
}

// ---------------- aggregation v2: 2 nodes/warp, 8-deep gather pipeline ----------------
// R8: agg kernels were latency-serialized (1 node/warp, 4 gathers in flight,
// agg2 issuing 2B/lane loads). Now: 32-lane halves each own a node -> agg1
// gathers uint2 (8B/lane, one inst per node-row), agg2 u32; 8 index loads
// issued before 8 gathers -> 2-4x memory-level parallelism per wave.
// 100000 = 12500 blocks * 8 nodes exactly (no tail guard needed).

__global__ __launch_bounds__(256) void agg1_kernel(
    const uint2* __restrict__ g1v, const int* __restrict__ row_ptr,
    const int* __restrict__ csr_src, const float* __restrict__ dinv,
    const float4* __restrict__ b1v, uint2* __restrict__ h1v) {
    int tid = threadIdx.x;
    int wv = tid >> 6;
    int lane = tid & 63;
    int half = lane >> 5;
    int hl = lane & 31;
    int node = blockIdx.x * 8 + wv * 2 + half;
    uint2 u = g1v[(size_t)node * 32 + hl];
    float a0 = lo_bf(u.x), a1 = hi_bf(u.x), a2 = lo_bf(u.y), a3 = hi_bf(u.y);
    int e = row_ptr[node], end = row_ptr[node + 1];
    for (; e + 8 <= end; e += 8) {
        int j0 = csr_src[e + 0], j1 = csr_src[e + 1], j2 = csr_src[e + 2], j3 = csr_src[e + 3];
        int j4 = csr_src[e + 4], j5 = csr_src[e + 5], j6 = csr_src[e + 6], j7 = csr_src[e + 7];
        uint2 v0 = g1v[(size_t)j0 * 32 + hl];
        uint2 v1 = g1v[(size_t)j1 * 32 + hl];
        uint2 v2 = g1v[(size_t)j2 * 32 + hl];
        uint2 v3 = g1v[(size_t)j3 * 32 + hl];
        uint2 v4 = g1v[(size_t)j4 * 32 + hl];
        uint2 v5 = g1v[(size_t)j5 * 32 + hl];
        uint2 v6 = g1v[(size_t)j6 * 32 + hl];
        uint2 v7 = g1v[(size_t)j7 * 32 + hl];
        a0 += ((lo_bf(v0.x) + lo_bf(v1.x)) + (lo_bf(v2.x) + lo_bf(v3.x))) +
              ((lo_bf(v4.x) + lo_bf(v5.x)) + (lo_bf(v6.x) + lo_bf(v7.x)));
        a1 += ((hi_bf(v0.x) + hi_bf(v1.x)) + (hi_bf(v2.x) + hi_bf(v3.x))) +
              ((hi_bf(v4.x) + hi_bf(v5.x)) + (hi_bf(v6.x) + hi_bf(v7.x)));
        a2 += ((lo_bf(v0.y) + lo_bf(v1.y)) + (lo_bf(v2.y) + lo_bf(v3.y))) +
              ((lo_bf(v4.y) + lo_bf(v5.y)) + (lo_bf(v6.y) + lo_bf(v7.y)));
        a3 += ((hi_bf(v0.y) + hi_bf(v1.y)) + (hi_bf(v2.y) + hi_bf(v3.y))) +
              ((hi_bf(v4.y) + hi_bf(v5.y)) + (hi_bf(v6.y) + hi_bf(v7.y)));
    }
    for (; e + 2 <= end; e += 2) {
        int j0 = csr_src[e + 0], j1 = csr_src[e + 1];
        uint2 v0 = g1v[(size_t)j0 * 32 + hl];
        uint2 v1 = g1v[(size_t)j1 * 32 + hl];
        a0 += lo_bf(v0.x) + lo_bf(v1.x);
        a1 += hi_bf(v0.x) + hi_bf(v1.x);
        a2 += lo_bf(v0.y) + lo_bf(v1.y);
        a3 += hi_bf(v0.y) + hi_bf(v1.y);
    }
    for (; e < end; ++e) {
        uint2 v0 = g1v[(size_t)csr_src[e] * 32 + hl];
        a0 += lo_bf(v0.x);
        a1 += hi_bf(v0.x);
        a2 += lo_bf(v0.y);
        a3 += hi_bf(v0.y);
    }
    float d = dinv[node];
    float4 b = b1v[hl];
    float r0 = fmaxf(d * a0 + b.x, 0.0f);
    float r1 = fmaxf(d * a1 + b.y, 0.0f);
    float r2 = fmaxf(d * a2 + b.z, 0.0f);
    float r3 = fmaxf(d * a3 + b.w, 0.0f);
    h1v[(size_t)node * 32 + hl] = uint2{pack_bf2(r0, r1), pack_bf2(r2, r3)};
}

__global__ __launch_bounds__(256) void agg2_lsm_kernel(
    const unsigned* __restrict__ g2v, const int* __restrict__ row_ptr,
    const int* __restrict__ csr_src, const float* __restrict__ dinv,
    const float2* __restrict__ b2v, float2* __restrict__ outv) {
    int tid = threadIdx.x;
    int wv = tid >> 6;
    int lane = tid & 63;
    int half = lane >> 5;
    int hl = lane & 31;
    int node = blockIdx.x * 8 + wv * 2 + half;
    unsigned u = g2v[(size_t)node * 32 + hl];
    float a0 = lo_bf(u), a1 = hi_bf(u);
    int e = row_ptr[node], end = row_ptr[node + 1];
    for (; e + 8 <= end; e += 8) {
        int j0 = csr_src[e + 0], j1 = csr_src[e + 1], j2 = csr_src[e + 2], j3 = csr_src[e + 3];
        int j4 = csr_src[e + 4], j5 = csr_src[e + 5], j6 = csr_src[e + 6], j7 = csr_src[e + 7];
        unsigned v0 = g2v[(size_t)j0 * 32 + hl];
        unsigned v1 = g2v[(size_t)j1 * 32 + hl];
        unsigned v2 = g2v[(size_t)j2 * 32 + hl];
        unsigned v3 = g2v[(size_t)j3 * 32 + hl];
        unsigned v4 = g2v[(size_t)j4 * 32 + hl];
        unsigned v5 = g2v[(size_t)j5 * 32 + hl];
        unsigned v6 = g2v[(size_t)j6 * 32 + hl];
        unsigned v7 = g2v[(size_t)j7 * 32 + hl];
        a0 += ((lo_bf(v0) + lo_bf(v1)) + (lo_bf(v2) + lo_bf(v3))) +
              ((lo_bf(v4) + lo_bf(v5)) + (lo_bf(v6) + lo_bf(v7)));
        a1 += ((hi_bf(v0) + hi_bf(v1)) + (hi_bf(v2) + hi_bf(v3))) +
              ((hi_bf(v4) + hi_bf(v5)) + (hi_bf(v6) + hi_bf(v7)));
    }
    for (; e + 2 <= end; e += 2) {
        unsigned v0 = g2v[(size_t)csr_src[e + 0] * 32 + hl];
        unsigned v1 = g2v[(size_t)csr_src[e + 1] * 32 + hl];
        a0 += lo_bf(v0) + lo_bf(v1);
        a1 += hi_bf(v0) + hi_bf(v1);
    }
    for (; e < end; ++e) {
        unsigned v0 = g2v[(size_t)csr_src[e] * 32 + hl];
        a0 += lo_bf(v0);
        a1 += hi_bf(v0);
    }
    float d = dinv[node];
    float2 b = b2v[hl];
    float v0 = d * a0 + b.x;
    float v1 = d * a1 + b.y;
    // log-softmax over 64 classes: per-lane pair + 32-lane half reduction
    // (xor offsets <=16 stay within the 32-lane half)
    float m = fmaxf(v0, v1);
#pragma unroll
    for (int o = 16; o > 0; o >>= 1) m = fmaxf(m, __shfl_xor(m, o, 64));
    float s = __expf(v0 - m) + __expf(v1 - m);
#pragma unroll
    for (int o = 16; o > 0; o >>= 1) s += __shfl_xor(s, o, 64);
    float ls = __logf(s);
    outv[(size_t)node * 32 + hl] = float2{v0 - m - ls, v1 - m - ls};
}

// ---------------- launch ----------------

extern "C" void kernel_launch(void* const* d_in, const int* in_sizes, int n_in,
                              void* d_out, int out_size, void* d_ws, size_t ws_size,
                              hipStream_t stream) {
    const float* x  = (const float*)d_in[0];
    const int* eidx = (const int*)d_in[1];
    const float* W1 = (const float*)d_in[2];
    const float* b1 = (const float*)d_in[3];
    const float* W2 = (const float*)d_in[4];
    const float* b2 = (const float*)d_in[5];
    float* out = (float*)d_out;
    const int* src = eidx;
    const int* dst = eidx + N_EDGES;

    char* base = (char*)d_ws;
    size_t off = 0;
    auto alloc = [&](size_t bytes) -> void* {
        void* p = base + off;
        off += (bytes + 255) & ~(size_t)255;
        return p;
    };
    // zero-init region: [deg | gcur | ovcnt] — one memset
    int* zbase    = (int*)alloc((size_t)(N_NODES + NBUK + 64) * 4);
    int* deg      = zbase;
    int* gcur     = zbase + N_NODES;
    int* ovcnt    = zbase + N_NODES + NBUK;
    int* row_ptr  = (int*)alloc((size_t)(N_NODES + 1) * 4);
    int* cursor   = (int*)alloc((size_t)N_NODES * 4);
    float* dinv   = (float*)alloc((size_t)N_NODES * 4);
    int* bsum     = (int*)alloc((size_t)SCAN_NB * 4);
    unsigned* staging = (unsigned*)alloc((size_t)NBUK * SCAP * 4);   // 9.6 MB
    unsigned long long* ovbuf = (unsigned long long*)alloc((size_t)OV_CAP * 8);
    int* csr_src  = (int*)alloc((size_t)N_EDGES * 4);
    unsigned short* Wt1 = (unsigned short*)alloc((size_t)F_HID * F_IN * 2);
    unsigned short* Wt2 = (unsigned short*)alloc((size_t)F_OUT * F_HID * 2);
    unsigned short* g1  = (unsigned short*)alloc((size_t)N_NODES * F_HID * 2);
    unsigned short* h1  = (unsigned short*)alloc((size_t)N_NODES * F_HID * 2);
    unsigned short* g2  = g1;  // g1 dead after agg1

    hipMemsetAsync(zbase, 0, (size_t)(N_NODES + NBUK + 64) * 4, stream);
    partition_kernel<<<NBLK_A, 256, 0, stream>>>(src, dst, deg, staging, gcur, ovbuf, ovcnt);
    block_sum_kernel<<<SCAN_NB, 256, 0, stream>>>(deg, bsum, N_NODES);
    scan_partials_kernel<<<1, 512, 0, stream>>>(bsum, SCAN_NB);
    scan_final_kernel<<<SCAN_NB, 256, 0, stream>>>(deg, bsum, row_ptr, cursor, dinv, N_NODES);
    fill_kernel<<<NBUK, 256, 0, stream>>>(staging, gcur, cursor, csr_src, ovbuf, ovcnt);
    transpose_w_kernel<<<(F_HID * F_IN + F_OUT * F_HID + 255) / 256, 256, 0, stream>>>(
        W1, W2, Wt1, Wt2);

    int gblocks = (N_NODES + 127) / 128;  // 782
    gemm_lds_kernel<F_HID, F_IN, false><<<gblocks, 256, 0, stream>>>(
        (const void*)x, Wt1, dinv, g1, N_NODES);
    agg1_kernel<<<N_NODES / 8, 256, 0, stream>>>(
        (const uint2*)g1, row_ptr, csr_src, dinv, (const float4*)b1, (uint2*)h1);

    gemm_lds_kernel<F_OUT, F_HID, true><<<gblocks, 256, 0, stream>>>(
        (const void*)h1, Wt2, dinv, g2, N_NODES);
    agg2_lsm_kernel<<<N_NODES / 8, 256, 0, stream>>>(
        (const unsigned*)g2, row_ptr, csr_src, dinv, (const float2*)b2, (float2*)out);
}